// Round 1
// 11454.063 us; speedup vs baseline: 2.5039x; 2.5039x over previous
//
#include <hip/hip_runtime.h>
#include <cstdint>

#define B_SZ 8192
#define T_SZ 2048

// ---- model constants ----
#define C_LTS       0.126f
#define C_LMIN      (0.5f * 0.089f)
#define C_LMAX      (1.6f * 0.089f)
#define C_KT        35.0f
#define C_CT        0.2f
#define C_VMAX_L0   (10.0f * 0.089f)
#define C_AF_INV    4.0f
#define C_FAT_RATE  0.01f
#define C_REC_RATE  0.002f
#define C_TAU_ACT   0.01f
#define C_TAU_DEACT 0.04f
#define C_L0SIN     0.0077598346f          // L0 * sin(0.0873)
#define C_LMT_DEF   0.2146610680f          // LTS + L0*cos(0.0873)
#define C_INV_EM5   0.006783655f           // 1/(e^5 - 1)
#define C_INV_LTS   (1.0f / 0.126f)
#define C_INV_L0    (1.0f / 0.089f)
#define C_NN_SCALE  0.02f                  // (1-PHYSICS_WEIGHT) * 0.1

typedef __attribute__((ext_vector_type(8))) short bf16x8;
typedef __attribute__((ext_vector_type(4))) float f32x4;

__device__ __forceinline__ float fast_rcp(float x) { return __builtin_amdgcn_rcpf(x); }
__device__ __forceinline__ float fast_tanh(float x) {
    const float e2 = __expf(2.0f * x);
    return 1.0f - 2.0f * fast_rcp(e2 + 1.0f);
}
__device__ __forceinline__ float clampf(float x, float lo, float hi) {
    return fminf(fmaxf(x, lo), hi);
}
__device__ __forceinline__ short f2bf_trunc(float f) {
    return (short)(__float_as_uint(f) >> 16);
}
__device__ __forceinline__ short f2bf_rne(float f) {
    uint32_t u = __float_as_uint(f);
    u += 0x7fff + ((u >> 16) & 1);
    return (short)(u >> 16);
}
__device__ __forceinline__ float bf2f(short s) {
    return __uint_as_float(((uint32_t)(unsigned short)s) << 16);
}

// Reduce-scatter over the 16 r-lanes of a q-group.
// Input: v0..v3 = values for reg 0..3 (element e = q*4+reg).
// Output on lane r: full 16-lane sum of value[reg = r&3].
// Levels 1,2 scatter the reg index from lane bits 0,1; levels 3,4 reduce bits 2,3.
__device__ __forceinline__ float scat16(float v0, float v1, float v2, float v3,
                                        bool bt0, bool bt1) {
    const float a0 = bt0 ? v1 : v0, s0 = bt0 ? v0 : v1;
    const float a1 = bt0 ? v3 : v2, s1 = bt0 ? v2 : v3;
    const float t0 = a0 + __shfl_xor(s0, 1, 64);
    const float t1 = a1 + __shfl_xor(s1, 1, 64);
    const float a  = bt1 ? t1 : t0, s = bt1 ? t0 : t1;
    float u = a + __shfl_xor(s, 2, 64);
    u += __shfl_xor(u, 4, 64);
    u += __shfl_xor(u, 8, 64);
    return u;
}

// 4 waves (256 threads) per block cooperating on 16 elements.
// Wave wv owns layer-2 output columns [wv*16, wv*16+16) and layer-1 units
// j = wv*16 + q*4 + {0..3}.  h1 (bf16 hi/lo A-fragments) is exchanged via LDS;
// layer-3 partial sums are combined via a small LDS psum buffer.
// Two __syncthreads per RK stage; write/read ordering makes single-buffer safe:
//   write h1 -> bar1 -> read A-frags -> MFMA -> psum write -> bar2 -> psum read
__global__ __launch_bounds__(256) void ode_kernel(
    const float* __restrict__ init_state,   // (B,3)
    const float* __restrict__ exc,          // (B,T)
    const float* __restrict__ tspan,        // (T,)
    const float* __restrict__ W1,           // (4,64)
    const float* __restrict__ b1,           // (64,)
    const float* __restrict__ W2,           // (64,64)
    const float* __restrict__ b2,           // (64,)
    const float* __restrict__ W3,           // (64,3)
    const float* __restrict__ b3,           // (3,)
    float* __restrict__ out)                // (T,B,3)
{
    const int tid  = threadIdx.x;
    const int wv   = tid >> 6;              // wave 0..3 = ct tile
    const int lane = tid & 63;
    const int r    = lane & 15;             // element-within-block / A-row / B-col
    const int q    = lane >> 4;             // k-octet selector
    const int el   = (blockIdx.x << 4) + r;

    // h1hi/h1lo: [16 el][64 units] shorts, 16B slots XOR-swizzled by (row&7).
    __shared__ __align__(16) short h1hi[1024];
    __shared__ __align__(16) short h1lo[1024];
    __shared__ __align__(16) float psum[256];   // [4 wv][16 el][4 pad] f32

    // ---- one-time weight preload ----
    float w1r[4][4], b1r[4];
    {
        const int j0 = (wv << 4) + (q << 2);
        #pragma unroll
        for (int u = 0; u < 4; ++u) {
            const int j = j0 + u;
            b1r[u]   = b1[j];
            w1r[0][u] = W1[j];
            w1r[1][u] = W1[64 + j];
            w1r[2][u] = W1[128 + j];
            w1r[3][u] = W1[192 + j];
        }
    }
    const int col = (wv << 4) + r;          // this lane's layer-2 output column
    bf16x8 Bh[2], Bl[2];
    #pragma unroll
    for (int ks = 0; ks < 2; ++ks)
        #pragma unroll
        for (int t = 0; t < 8; ++t) {
            const int k = (ks << 5) + (q << 3) + t;
            const float wgt = W2[(k << 6) + col];
            const short hi = f2bf_trunc(wgt);
            Bh[ks][t] = hi;
            Bl[ks][t] = f2bf_rne(wgt - bf2f(hi));
        }
    const float b2v  = b2[col];
    const float w3c0 = W3[col * 3 + 0], w3c1 = W3[col * 3 + 1], w3c2 = W3[col * 3 + 2];
    const float b3v0 = b3[0], b3v1 = b3[1], b3v2 = b3[2];

    // ---- LDS addresses (short/float indices), hoisted out of the loop ----
    const int slotW = (wv << 1) + (q >> 1);                       // write 16B slot
    const int widx  = (r << 6) + ((slotW ^ (r & 7)) << 3) + ((q & 1) << 2);
    const int ridx0 = (r << 6) + ((q       ^ (r & 7)) << 3);      // ks=0 A-frag
    const int ridx1 = (r << 6) + (((4 | q) ^ (r & 7)) << 3);      // ks=1 A-frag
    const int pwidx = (wv << 6) + (((q << 2) + r) << 2);          // valid when r<4
    const bool bt0 = (lane & 1) != 0;
    const bool bt1 = (lane & 2) != 0;

    // ---- state (replicated across q and waves; identical arithmetic everywhere) ----
    float yb0 = init_state[el * 3 + 0];
    float yb1 = init_state[el * 3 + 1];
    float yb2 = init_state[el * 3 + 2];
    float cs0 = yb0, cs1 = yb1, cs2 = yb2;
    float ka0 = 0.f, ka1 = 0.f, ka2 = 0.f;

    if (wv == 0 && q == 0) {
        out[(size_t)el * 3 + 0] = yb0;
        out[(size_t)el * 3 + 1] = yb1;
        out[(size_t)el * 3 + 2] = yb2;
    }

    float excB = exc[(size_t)el * T_SZ];    // k2..k4 column for step 0
    float excA = excB;                      // k1 column (clipped idx at step 0)
    float tA = tspan[0], tB = tspan[1];

    #pragma unroll 1
    for (int i = 0; i < T_SZ - 1; ++i) {
        // prefetch next step's exc column and t (branch-free clamped index)
        const float excN = exc[(size_t)el * T_SZ + ((i < T_SZ - 2) ? (i + 1) : (T_SZ - 2))];
        const float tN   = tspan[(i <= T_SZ - 3) ? (i + 2) : (T_SZ - 1)];
        const float dt  = tB - tA;
        const float hdt = 0.5f * dt;

        #pragma unroll
        for (int ev = 0; ev < 4; ++ev) {
            const float excv = (ev == 0) ? excA : excB;
            const float s0 = cs0, s1 = cs1, s2 = cs2;

            // ---- layer 1: this wave's 4 units for element r ----
            uint32_t hi01, hi23, lo01, lo23;
            {
                float hv[4];
                #pragma unroll
                for (int u = 0; u < 4; ++u) {
                    float pre = b1r[u];
                    pre = fmaf(s0,   w1r[0][u], pre);
                    pre = fmaf(s1,   w1r[1][u], pre);
                    pre = fmaf(s2,   w1r[2][u], pre);
                    pre = fmaf(excv, w1r[3][u], pre);
                    hv[u] = fast_tanh(pre);
                }
                const unsigned short h0 = (unsigned short)f2bf_trunc(hv[0]);
                const unsigned short h1_ = (unsigned short)f2bf_trunc(hv[1]);
                const unsigned short h2_ = (unsigned short)f2bf_trunc(hv[2]);
                const unsigned short h3_ = (unsigned short)f2bf_trunc(hv[3]);
                hi01 = (uint32_t)h0 | ((uint32_t)h1_ << 16);
                hi23 = (uint32_t)h2_ | ((uint32_t)h3_ << 16);
                const unsigned short l0 = (unsigned short)f2bf_rne(hv[0] - bf2f((short)h0));
                const unsigned short l1 = (unsigned short)f2bf_rne(hv[1] - bf2f((short)h1_));
                const unsigned short l2 = (unsigned short)f2bf_rne(hv[2] - bf2f((short)h2_));
                const unsigned short l3 = (unsigned short)f2bf_rne(hv[3] - bf2f((short)h3_));
                lo01 = (uint32_t)l0 | ((uint32_t)l1 << 16);
                lo23 = (uint32_t)l2 | ((uint32_t)l3 << 16);
            }
            *reinterpret_cast<uint2*>(&h1hi[widx]) = make_uint2(hi01, hi23);
            *reinterpret_cast<uint2*>(&h1lo[widx]) = make_uint2(lo01, lo23);
            __syncthreads();                              // bar1: h1 ready

            // ---- layer 2: one 16x16 ct tile, hi/lo split, two K-half chains ----
            const bf16x8 Ah0 = *reinterpret_cast<const bf16x8*>(&h1hi[ridx0]);
            const bf16x8 Ah1 = *reinterpret_cast<const bf16x8*>(&h1hi[ridx1]);
            const bf16x8 Al0 = *reinterpret_cast<const bf16x8*>(&h1lo[ridx0]);
            const bf16x8 Al1 = *reinterpret_cast<const bf16x8*>(&h1lo[ridx1]);

            f32x4 accA = {b2v, b2v, b2v, b2v};
            f32x4 accB = {0.f, 0.f, 0.f, 0.f};
            accA = __builtin_amdgcn_mfma_f32_16x16x32_bf16(Al0, Bh[0], accA, 0, 0, 0);
            accB = __builtin_amdgcn_mfma_f32_16x16x32_bf16(Al1, Bh[1], accB, 0, 0, 0);
            accA = __builtin_amdgcn_mfma_f32_16x16x32_bf16(Ah0, Bl[0], accA, 0, 0, 0);
            accB = __builtin_amdgcn_mfma_f32_16x16x32_bf16(Ah1, Bl[1], accB, 0, 0, 0);
            accA = __builtin_amdgcn_mfma_f32_16x16x32_bf16(Ah0, Bh[0], accA, 0, 0, 0);
            accB = __builtin_amdgcn_mfma_f32_16x16x32_bf16(Ah1, Bh[1], accB, 0, 0, 0);

            // ---- layer-2 tanh + layer-3 partials (rows e = q*4+reg, col = wv*16+r) ----
            float p0[4], p1[4], p2[4];
            #pragma unroll
            for (int reg = 0; reg < 4; ++reg) {
                const float h2v = fast_tanh(accA[reg] + accB[reg]);
                p0[reg] = h2v * w3c0;
                p1[reg] = h2v * w3c1;
                p2[reg] = h2v * w3c2;
            }

            // ---- reduce-scatter over the 16 cols held across r-lanes ----
            const float Sp0 = scat16(p0[0], p0[1], p0[2], p0[3], bt0, bt1);
            const float Sp1 = scat16(p1[0], p1[1], p1[2], p1[3], bt0, bt1);
            const float Sp2 = scat16(p2[0], p2[1], p2[2], p2[3], bt0, bt1);
            // lane (q,r) now holds this wave's col-sum for element e = q*4 + (r&3);
            // lanes r<4 (e = q*4+r) are the unique writers.
            if (r < 4) {
                *reinterpret_cast<float2*>(&psum[pwidx]) = make_float2(Sp0, Sp1);
                psum[pwidx + 2] = Sp2;
            }
            __syncthreads();                              // bar2: psum ready

            // ---- combine the 4 wave-partials for this lane's element (e = r) ----
            const f32x4 v0 = *reinterpret_cast<const f32x4*>(&psum[(r << 2)]);
            const f32x4 v1 = *reinterpret_cast<const f32x4*>(&psum[64 + (r << 2)]);
            const f32x4 v2 = *reinterpret_cast<const f32x4*>(&psum[128 + (r << 2)]);
            const f32x4 v3 = *reinterpret_cast<const f32x4*>(&psum[192 + (r << 2)]);
            const float S0 = (v0[0] + v1[0]) + (v2[0] + v3[0]);
            const float S1 = (v0[1] + v1[1]) + (v2[1] + v3[1]);
            const float S2 = (v0[2] + v1[2]) + (v2[2] + v3[2]);

            const float nn0 = C_NN_SCALE * fast_tanh(S0 + b3v0);
            const float nn1 = C_NN_SCALE * fast_tanh(S1 + b3v1);
            const float nn2 = C_NN_SCALE * fast_tanh(S2 + b3v2);

            // ---- physics on raw stage state (replicated; rcp-based divides) ----
            const float lM  = clampf(s0, C_LMIN, C_LMAX);
            const float act = clampf(s1, 0.01f, 1.0f);
            const float fat = clampf(s2, 0.0f, 1.0f);
            const float a_eff = act * (1.0f - fat);
            const float sin_p = clampf(C_L0SIN * fast_rcp(lM), 0.0f, 0.99f);
            const float cp2   = 1.0f - sin_p * sin_p;
            const float cos_p = sqrtf(cp2);
            const float inv_cp = fast_rcp(cos_p);
            const float lT   = C_LMT_DEF - lM * cos_p;
            const float epsT = (lT - C_LTS) * C_INV_LTS;
            const float fT   = (epsT > 0.0f) ? C_CT * (__expf(C_KT * epsT) - 1.0f) : 0.0f;
            const float lN   = lM * C_INV_L0;
            const float d1   = lN - 1.0f;
            const float fL   = __expf(-d1 * d1 * (1.0f / 0.45f));
            const float fPE  = (lN > 1.0f) ? (__expf(8.3333333333f * d1) - 1.0f) * C_INV_EM5 : 0.0f;
            const float fV   = (fT * inv_cp - fPE) * fast_rcp(fmaf(a_eff, fL, 0.001f));
            float vN = (fV - 1.0f) * fast_rcp(fmaf(fabsf(fV), C_AF_INV, 1.0f));
            vN = clampf(vN, -1.0f, 1.5f);
            const float r0v = fmaf(C_VMAX_L0, vN, nn0);
            const float g15 = fmaf(1.5f, act, 0.5f);
            const float inv_tau = (excv > act) ? fast_rcp(C_TAU_ACT * g15)
                                               : g15 * (1.0f / C_TAU_DEACT);
            const float r1v = fmaf(excv - act, inv_tau, nn1);
            const float r2v = C_FAT_RATE * a_eff * (1.0f - fat)
                            - C_REC_RATE * (1.0f - a_eff) * fat + nn2;

            // ---- RK4 bookkeeping (identical across all replicas) ----
            if (ev == 0) {
                ka0 = r0v; ka1 = r1v; ka2 = r2v;
                cs0 = fmaf(hdt, r0v, yb0); cs1 = fmaf(hdt, r1v, yb1); cs2 = fmaf(hdt, r2v, yb2);
            } else if (ev == 1) {
                ka0 = fmaf(2.0f, r0v, ka0); ka1 = fmaf(2.0f, r1v, ka1); ka2 = fmaf(2.0f, r2v, ka2);
                cs0 = fmaf(hdt, r0v, yb0); cs1 = fmaf(hdt, r1v, yb1); cs2 = fmaf(hdt, r2v, yb2);
            } else if (ev == 2) {
                ka0 = fmaf(2.0f, r0v, ka0); ka1 = fmaf(2.0f, r1v, ka1); ka2 = fmaf(2.0f, r2v, ka2);
                cs0 = fmaf(dt, r0v, yb0); cs1 = fmaf(dt, r1v, yb1); cs2 = fmaf(dt, r2v, yb2);
            } else {
                const float c6 = dt * (1.0f / 6.0f);
                yb0 = fmaf(c6, ka0 + r0v, yb0);
                yb1 = fmaf(c6, ka1 + r1v, yb1);
                yb2 = fmaf(c6, ka2 + r2v, yb2);
                cs0 = yb0; cs1 = yb1; cs2 = yb2;
                if (wv == 0 && q == 0) {
                    const size_t ob = (size_t)(i + 1) * (B_SZ * 3) + (size_t)el * 3;
                    out[ob + 0] = yb0; out[ob + 1] = yb1; out[ob + 2] = yb2;
                }
            }
        }

        excA = excB; excB = excN; tA = tB; tB = tN;
    }
}

extern "C" void kernel_launch(void* const* d_in, const int* in_sizes, int n_in,
                              void* d_out, int out_size, void* d_ws, size_t ws_size,
                              hipStream_t stream) {
    const float* init  = (const float*)d_in[0];
    const float* exc   = (const float*)d_in[1];
    const float* tspan = (const float*)d_in[2];
    const float* W1    = (const float*)d_in[3];
    const float* b1    = (const float*)d_in[4];
    const float* W2    = (const float*)d_in[5];
    const float* b2    = (const float*)d_in[6];
    const float* W3    = (const float*)d_in[7];
    const float* b3    = (const float*)d_in[8];

    hipLaunchKernelGGL(ode_kernel, dim3(B_SZ / 16), dim3(256), 0, stream,
                       init, exc, tspan, W1, b1, W2, b2, W3, b3, (float*)d_out);
}

// Round 2
// 9483.273 us; speedup vs baseline: 3.0242x; 1.2078x over previous
//
#include <hip/hip_runtime.h>
#include <cstdint>

#define B_SZ 8192
#define T_SZ 2048

// ---- model constants ----
#define C_LTS       0.126f
#define C_LMIN      (0.5f * 0.089f)
#define C_LMAX      (1.6f * 0.089f)
#define C_KT        35.0f
#define C_CT        0.2f
#define C_VMAX_L0   (10.0f * 0.089f)
#define C_AF_INV    4.0f
#define C_FAT_RATE  0.01f
#define C_REC_RATE  0.002f
#define C_TAU_ACT   0.01f
#define C_TAU_DEACT 0.04f
#define C_L0SIN     0.0077598346f          // L0 * sin(0.0873)
#define C_LMT_DEF   0.2146610680f          // LTS + L0*cos(0.0873)
#define C_INV_EM5   0.006783655f           // 1/(e^5 - 1)
#define C_INV_LTS   (1.0f / 0.126f)
#define C_INV_L0    (1.0f / 0.089f)
#define C_NN_SCALE  0.02f                  // (1-PHYSICS_WEIGHT) * 0.1

typedef __attribute__((ext_vector_type(8))) short bf16x8;
typedef __attribute__((ext_vector_type(4))) float f32x4;

__device__ __forceinline__ float fast_rcp(float x) { return __builtin_amdgcn_rcpf(x); }
__device__ __forceinline__ float fast_rsq(float x) { return __builtin_amdgcn_rsqf(x); }
__device__ __forceinline__ float fast_tanh(float x) {
    const float e2 = __expf(2.0f * x);
    return 1.0f - 2.0f * fast_rcp(e2 + 1.0f);
}
__device__ __forceinline__ float clampf(float x, float lo, float hi) {
    return fminf(fmaxf(x, lo), hi);
}
__device__ __forceinline__ short f2bf_trunc(float f) {
    return (short)(__float_as_uint(f) >> 16);
}
__device__ __forceinline__ short f2bf_rne(float f) {
    uint32_t u = __float_as_uint(f);
    u += 0x7fff + ((u >> 16) & 1);
    return (short)(u >> 16);
}
__device__ __forceinline__ float bf2f(short s) {
    return __uint_as_float(((uint32_t)(unsigned short)s) << 16);
}

// 4 waves (256 threads) per block cooperating on 16 elements.
// TRANSPOSED GEMM: compute h2^T = W2^T(64x64) . h1^T(64x16el).
// A-operand = W2^T tile (wave wv owns cols 16wv..16wv+15), B-operand = h1^T.
// A-frag and B-frag layouts of mfma_16x16x32 are index-symmetric, so the W2
// register fragments and the h1 LDS exchange are IDENTICAL to the
// non-transposed version; only the mfma operand order changes.
// D layout: lane(q,r) holds h2[col = 16wv + 4q + reg][elem = r] -> layer-3
// partials are lane-local in the element axis; the column reduce is just
// shfl_xor(16) + shfl_xor(32), then a 4-wave psum combine in LDS.
// Two __syncthreads per RK stage:
//   write h1 -> bar1 -> read B-frags -> MFMA -> reduce -> psum write -> bar2
__global__ __launch_bounds__(256) void ode_kernel(
    const float* __restrict__ init_state,   // (B,3)
    const float* __restrict__ exc,          // (B,T)
    const float* __restrict__ tspan,        // (T,)
    const float* __restrict__ W1,           // (4,64)
    const float* __restrict__ b1,           // (64,)
    const float* __restrict__ W2,           // (64,64)
    const float* __restrict__ b2,           // (64,)
    const float* __restrict__ W3,           // (64,3)
    const float* __restrict__ b3,           // (3,)
    float* __restrict__ out)                // (T,B,3)
{
    const int tid  = threadIdx.x;
    const int wv   = tid >> 6;              // wave 0..3 = column tile
    const int lane = tid & 63;
    const int r    = lane & 15;             // element-within-block
    const int q    = lane >> 4;             // k-octet selector
    const int el   = (blockIdx.x << 4) + r;

    // h1hi/h1lo: [16 el][64 units] shorts, 16B slots XOR-swizzled by (row&7).
    __shared__ __align__(16) short h1hi[1024];
    __shared__ __align__(16) short h1lo[1024];
    __shared__ __align__(16) float psum[256];   // [4 wv][16 el][4] f32

    // ---- one-time weight preload ----
    float w1r[4][4], b1r[4];
    {
        const int j0 = (wv << 4) + (q << 2);
        #pragma unroll
        for (int u = 0; u < 4; ++u) {
            const int j = j0 + u;
            b1r[u]   = b1[j];
            w1r[0][u] = W1[j];
            w1r[1][u] = W1[64 + j];
            w1r[2][u] = W1[128 + j];
            w1r[3][u] = W1[192 + j];
        }
    }
    // W2^T A-fragments: lane(q,r) holds A[m = r][k = ks*32 + q*8 + t]
    //   = W2[k][col = 16wv + r]   (identical values to the old B-fragments)
    const int col = (wv << 4) + r;
    bf16x8 Wh[2], Wl[2];
    #pragma unroll
    for (int ks = 0; ks < 2; ++ks)
        #pragma unroll
        for (int t = 0; t < 8; ++t) {
            const int k = (ks << 5) + (q << 3) + t;
            const float wgt = W2[(k << 6) + col];
            const short hi = f2bf_trunc(wgt);
            Wh[ks][t] = hi;
            Wl[ks][t] = f2bf_rne(wgt - bf2f(hi));
        }
    // per-lane D rows: c = 16wv + 4q + reg  (reg = 0..3)
    float b2v4[4], w3r[4][3];
    #pragma unroll
    for (int reg = 0; reg < 4; ++reg) {
        const int c = (wv << 4) + (q << 2) + reg;
        b2v4[reg]  = b2[c];
        w3r[reg][0] = W3[c * 3 + 0];
        w3r[reg][1] = W3[c * 3 + 1];
        w3r[reg][2] = W3[c * 3 + 2];
    }
    const float b3v0 = b3[0], b3v1 = b3[1], b3v2 = b3[2];

    // ---- LDS addresses (short/float indices), hoisted out of the loop ----
    const int slotW = (wv << 1) + (q >> 1);                       // write 16B slot
    const int widx  = (r << 6) + ((slotW ^ (r & 7)) << 3) + ((q & 1) << 2);
    const int ridx0 = (r << 6) + ((q       ^ (r & 7)) << 3);      // ks=0 B-frag
    const int ridx1 = (r << 6) + (((4 | q) ^ (r & 7)) << 3);      // ks=1 B-frag
    const int pswidx = (wv << 6) + (r << 2);                      // q==0 writers

    // ---- state (replicated across q and waves; identical arithmetic) ----
    float yb0 = init_state[el * 3 + 0];
    float yb1 = init_state[el * 3 + 1];
    float yb2 = init_state[el * 3 + 2];
    float cs0 = yb0, cs1 = yb1, cs2 = yb2;
    float ka0 = 0.f, ka1 = 0.f, ka2 = 0.f;

    if (wv == 0 && q == 0) {
        out[(size_t)el * 3 + 0] = yb0;
        out[(size_t)el * 3 + 1] = yb1;
        out[(size_t)el * 3 + 2] = yb2;
    }

    const float* excp = exc + (size_t)el * T_SZ;
    float excB = excp[0];                   // k2..k4 column for step 0
    float excA = excB;                      // k1 column (clipped idx at step 0)
    float tA = tspan[0], tB = tspan[1];

    #pragma unroll 1
    for (int i = 0; i < T_SZ - 1; ++i) {
        // prefetch next step's exc column and t (branch-free clamped index)
        const float excN = excp[(i < T_SZ - 2) ? (i + 1) : (T_SZ - 2)];
        const float tN   = tspan[(i <= T_SZ - 3) ? (i + 2) : (T_SZ - 1)];
        const float dt  = tB - tA;
        const float hdt = 0.5f * dt;

        #pragma unroll
        for (int ev = 0; ev < 4; ++ev) {
            const float excv = (ev == 0) ? excA : excB;
            const float s0 = cs0, s1 = cs1, s2 = cs2;

            // ---- layer 1: this wave's 4 units for element r ----
            uint32_t hi01, hi23, lo01, lo23;
            {
                float hv[4];
                #pragma unroll
                for (int u = 0; u < 4; ++u) {
                    float pre = b1r[u];
                    pre = fmaf(s0,   w1r[0][u], pre);
                    pre = fmaf(s1,   w1r[1][u], pre);
                    pre = fmaf(s2,   w1r[2][u], pre);
                    pre = fmaf(excv, w1r[3][u], pre);
                    hv[u] = fast_tanh(pre);
                }
                const unsigned short h0 = (unsigned short)f2bf_trunc(hv[0]);
                const unsigned short h1_ = (unsigned short)f2bf_trunc(hv[1]);
                const unsigned short h2_ = (unsigned short)f2bf_trunc(hv[2]);
                const unsigned short h3_ = (unsigned short)f2bf_trunc(hv[3]);
                hi01 = (uint32_t)h0 | ((uint32_t)h1_ << 16);
                hi23 = (uint32_t)h2_ | ((uint32_t)h3_ << 16);
                const unsigned short l0 = (unsigned short)f2bf_rne(hv[0] - bf2f((short)h0));
                const unsigned short l1 = (unsigned short)f2bf_rne(hv[1] - bf2f((short)h1_));
                const unsigned short l2 = (unsigned short)f2bf_rne(hv[2] - bf2f((short)h2_));
                const unsigned short l3 = (unsigned short)f2bf_rne(hv[3] - bf2f((short)h3_));
                lo01 = (uint32_t)l0 | ((uint32_t)l1 << 16);
                lo23 = (uint32_t)l2 | ((uint32_t)l3 << 16);
            }
            *reinterpret_cast<uint2*>(&h1hi[widx]) = make_uint2(hi01, hi23);
            *reinterpret_cast<uint2*>(&h1lo[widx]) = make_uint2(lo01, lo23);
            __syncthreads();                              // bar1: h1 ready

            // ---- layer 2 (transposed): A = W2^T frags, B = h1 frags ----
            const bf16x8 Hh0 = *reinterpret_cast<const bf16x8*>(&h1hi[ridx0]);
            const bf16x8 Hh1 = *reinterpret_cast<const bf16x8*>(&h1hi[ridx1]);
            const bf16x8 Hl0 = *reinterpret_cast<const bf16x8*>(&h1lo[ridx0]);
            const bf16x8 Hl1 = *reinterpret_cast<const bf16x8*>(&h1lo[ridx1]);

            f32x4 accA = {b2v4[0], b2v4[1], b2v4[2], b2v4[3]};
            f32x4 accB = {0.f, 0.f, 0.f, 0.f};
            accA = __builtin_amdgcn_mfma_f32_16x16x32_bf16(Wh[0], Hl0, accA, 0, 0, 0);
            accB = __builtin_amdgcn_mfma_f32_16x16x32_bf16(Wh[1], Hl1, accB, 0, 0, 0);
            accA = __builtin_amdgcn_mfma_f32_16x16x32_bf16(Wl[0], Hh0, accA, 0, 0, 0);
            accB = __builtin_amdgcn_mfma_f32_16x16x32_bf16(Wl[1], Hh1, accB, 0, 0, 0);
            accA = __builtin_amdgcn_mfma_f32_16x16x32_bf16(Wh[0], Hh0, accA, 0, 0, 0);
            accB = __builtin_amdgcn_mfma_f32_16x16x32_bf16(Wh[1], Hh1, accB, 0, 0, 0);

            // ---- layer-2 tanh + layer-3 partials (lane-local: cols 16wv+4q+reg,
            //      element = r) ----
            float p0 = 0.f, p1 = 0.f, p2 = 0.f;
            #pragma unroll
            for (int reg = 0; reg < 4; ++reg) {
                const float h2v = fast_tanh(accA[reg] + accB[reg]);
                p0 = fmaf(h2v, w3r[reg][0], p0);
                p1 = fmaf(h2v, w3r[reg][1], p1);
                p2 = fmaf(h2v, w3r[reg][2], p2);
            }
            // reduce over the 4 q-groups (cols spread across lanes r, r+16, r+32, r+48)
            p0 += __shfl_xor(p0, 16, 64);
            p1 += __shfl_xor(p1, 16, 64);
            p2 += __shfl_xor(p2, 16, 64);
            p0 += __shfl_xor(p0, 32, 64);
            p1 += __shfl_xor(p1, 32, 64);
            p2 += __shfl_xor(p2, 32, 64);
            // every lane now holds this wave's 16-col partial for element r
            if (q == 0) {
                *reinterpret_cast<f32x4*>(&psum[pswidx]) = (f32x4){p0, p1, p2, p2};
            }
            __syncthreads();                              // bar2: psum ready

            // ---- combine the 4 wave-partials for this lane's element r ----
            const f32x4 v0 = *reinterpret_cast<const f32x4*>(&psum[(r << 2)]);
            const f32x4 v1 = *reinterpret_cast<const f32x4*>(&psum[64 + (r << 2)]);
            const f32x4 v2 = *reinterpret_cast<const f32x4*>(&psum[128 + (r << 2)]);
            const f32x4 v3 = *reinterpret_cast<const f32x4*>(&psum[192 + (r << 2)]);
            const float S0 = (v0[0] + v1[0]) + (v2[0] + v3[0]);
            const float S1 = (v0[1] + v1[1]) + (v2[1] + v3[1]);
            const float S2 = (v0[2] + v1[2]) + (v2[2] + v3[2]);

            const float nn0 = C_NN_SCALE * fast_tanh(S0 + b3v0);
            const float nn1 = C_NN_SCALE * fast_tanh(S1 + b3v1);
            const float nn2 = C_NN_SCALE * fast_tanh(S2 + b3v2);

            // ---- physics on raw stage state (replicated; rcp/rsq divides) ----
            const float lM  = clampf(s0, C_LMIN, C_LMAX);
            const float act = clampf(s1, 0.01f, 1.0f);
            const float fat = clampf(s2, 0.0f, 1.0f);
            const float a_eff = act * (1.0f - fat);
            const float sin_p = fminf(C_L0SIN * fast_rcp(lM), 0.99f);  // >0 by lM clamp
            const float cp2   = fmaf(-sin_p, sin_p, 1.0f);
            const float inv_cp = fast_rsq(cp2);
            const float cos_p  = cp2 * inv_cp;
            const float lT   = C_LMT_DEF - lM * cos_p;
            const float epsT = (lT - C_LTS) * C_INV_LTS;
            const float fT   = (epsT > 0.0f) ? C_CT * (__expf(C_KT * epsT) - 1.0f) : 0.0f;
            const float lN   = lM * C_INV_L0;
            const float d1   = lN - 1.0f;
            const float fL   = __expf(-d1 * d1 * (1.0f / 0.45f));
            const float fPE  = (lN > 1.0f) ? (__expf(8.3333333333f * d1) - 1.0f) * C_INV_EM5 : 0.0f;
            const float fV   = (fT * inv_cp - fPE) * fast_rcp(fmaf(a_eff, fL, 0.001f));
            float vN = (fV - 1.0f) * fast_rcp(fmaf(fabsf(fV), C_AF_INV, 1.0f));
            vN = clampf(vN, -1.0f, 1.5f);
            const float r0v = fmaf(C_VMAX_L0, vN, nn0);
            const float g15 = fmaf(1.5f, act, 0.5f);
            const float inv_tau = (excv > act) ? fast_rcp(C_TAU_ACT * g15)
                                               : g15 * (1.0f / C_TAU_DEACT);
            const float r1v = fmaf(excv - act, inv_tau, nn1);
            const float r2v = C_FAT_RATE * a_eff * (1.0f - fat)
                            - C_REC_RATE * (1.0f - a_eff) * fat + nn2;

            // ---- RK4 bookkeeping (identical across all replicas) ----
            if (ev == 0) {
                ka0 = r0v; ka1 = r1v; ka2 = r2v;
                cs0 = fmaf(hdt, r0v, yb0); cs1 = fmaf(hdt, r1v, yb1); cs2 = fmaf(hdt, r2v, yb2);
            } else if (ev == 1) {
                ka0 = fmaf(2.0f, r0v, ka0); ka1 = fmaf(2.0f, r1v, ka1); ka2 = fmaf(2.0f, r2v, ka2);
                cs0 = fmaf(hdt, r0v, yb0); cs1 = fmaf(hdt, r1v, yb1); cs2 = fmaf(hdt, r2v, yb2);
            } else if (ev == 2) {
                ka0 = fmaf(2.0f, r0v, ka0); ka1 = fmaf(2.0f, r1v, ka1); ka2 = fmaf(2.0f, r2v, ka2);
                cs0 = fmaf(dt, r0v, yb0); cs1 = fmaf(dt, r1v, yb1); cs2 = fmaf(dt, r2v, yb2);
            } else {
                const float c6 = dt * (1.0f / 6.0f);
                yb0 = fmaf(c6, ka0 + r0v, yb0);
                yb1 = fmaf(c6, ka1 + r1v, yb1);
                yb2 = fmaf(c6, ka2 + r2v, yb2);
                cs0 = yb0; cs1 = yb1; cs2 = yb2;
                if (wv == 0 && q == 0) {
                    const size_t ob = (size_t)(i + 1) * (B_SZ * 3) + (size_t)el * 3;
                    out[ob + 0] = yb0; out[ob + 1] = yb1; out[ob + 2] = yb2;
                }
            }
        }

        excA = excB; excB = excN; tA = tB; tB = tN;
    }
}

extern "C" void kernel_launch(void* const* d_in, const int* in_sizes, int n_in,
                              void* d_out, int out_size, void* d_ws, size_t ws_size,
                              hipStream_t stream) {
    const float* init  = (const float*)d_in[0];
    const float* exc   = (const float*)d_in[1];
    const float* tspan = (const float*)d_in[2];
    const float* W1    = (const float*)d_in[3];
    const float* b1    = (const float*)d_in[4];
    const float* W2    = (const float*)d_in[5];
    const float* b2    = (const float*)d_in[6];
    const float* W3    = (const float*)d_in[7];
    const float* b3    = (const float*)d_in[8];

    hipLaunchKernelGGL(ode_kernel, dim3(B_SZ / 16), dim3(256), 0, stream,
                       init, exc, tspan, W1, b1, W2, b2, W3, b3, (float*)d_out);
}

// Round 3
// 9421.867 us; speedup vs baseline: 3.0439x; 1.0065x over previous
//
#include <hip/hip_runtime.h>
#include <cstdint>

#define B_SZ 8192
#define T_SZ 2048

// ---- model constants ----
#define C_LTS       0.126f
#define C_LMIN      (0.5f * 0.089f)
#define C_LMAX      (1.6f * 0.089f)
#define C_KT        35.0f
#define C_CT        0.2f
#define C_VMAX_L0   (10.0f * 0.089f)
#define C_AF_INV    4.0f
#define C_FAT_RATE  0.01f
#define C_REC_RATE  0.002f
#define C_TAU_ACT   0.01f
#define C_TAU_DEACT 0.04f
#define C_L0SIN     0.0077598346f          // L0 * sin(0.0873)
#define C_LMT_DEF   0.2146610680f          // LTS + L0*cos(0.0873)
#define C_INV_EM5   0.006783655f           // 1/(e^5 - 1)
#define C_INV_LTS   (1.0f / 0.126f)
#define C_INV_L0    (1.0f / 0.089f)
#define C_NN_SCALE  0.02f                  // (1-PHYSICS_WEIGHT) * 0.1

typedef __attribute__((ext_vector_type(8))) short bf16x8;
typedef __attribute__((ext_vector_type(4))) float f32x4;

__device__ __forceinline__ float fast_rcp(float x) { return __builtin_amdgcn_rcpf(x); }
__device__ __forceinline__ float fast_rsq(float x) { return __builtin_amdgcn_rsqf(x); }
__device__ __forceinline__ float fast_tanh(float x) {
    const float e2 = __expf(2.0f * x);
    return 1.0f - 2.0f * fast_rcp(e2 + 1.0f);
}
__device__ __forceinline__ float clampf(float x, float lo, float hi) {
    return fminf(fmaxf(x, lo), hi);
}
__device__ __forceinline__ short f2bf_trunc(float f) {
    return (short)(__float_as_uint(f) >> 16);
}
__device__ __forceinline__ short f2bf_rne(float f) {
    uint32_t u = __float_as_uint(f);
    u += 0x7fff + ((u >> 16) & 1);
    return (short)(u >> 16);
}
__device__ __forceinline__ float bf2f(short s) {
    return __uint_as_float(((uint32_t)(unsigned short)s) << 16);
}

// 4 waves (256 threads) per block cooperating on 16 elements.
// TRANSPOSED GEMM (as round 2) + PHYSICS SPECIALIZATION:
//   - all waves: layer1 (own 4 units/el), h1 exchange, own 16-col MFMA tile,
//     h2 tanh, layer3 partials, wave reduce, psum write.
//   - wave 0 ONLY: psum combine -> S -> nn -> physics -> RK4 -> new state,
//     published via cs_lds[16][4]; also the output store.
//   - waves 1-3: wave-uniform skip (execz) of the whole tail; after bar3 they
//     load cs with one ds_read_b128 (broadcast + 2-way aliasing = free).
// Three barriers/stage (h1, psum, cs) — the minimum for this dep chain.
// Arithmetic is bit-identical to the replicated version.
__global__ __launch_bounds__(256) void ode_kernel(
    const float* __restrict__ init_state,   // (B,3)
    const float* __restrict__ exc,          // (B,T)
    const float* __restrict__ tspan,        // (T,)
    const float* __restrict__ W1,           // (4,64)
    const float* __restrict__ b1,           // (64,)
    const float* __restrict__ W2,           // (64,64)
    const float* __restrict__ b2,           // (64,)
    const float* __restrict__ W3,           // (64,3)
    const float* __restrict__ b3,           // (3,)
    float* __restrict__ out)                // (T,B,3)
{
    const int tid  = threadIdx.x;
    const int wv   = tid >> 6;              // wave 0..3 = column tile
    const int lane = tid & 63;
    const int r    = lane & 15;             // element-within-block
    const int q    = lane >> 4;             // k-octet selector
    const int el   = (blockIdx.x << 4) + r;

    // h1hi/h1lo: [16 el][64 units] shorts, 16B slots XOR-swizzled by (row&7).
    __shared__ __align__(16) short h1hi[1024];
    __shared__ __align__(16) short h1lo[1024];
    __shared__ __align__(16) float psum[256];   // [4 wv][16 el][4] f32
    __shared__ __align__(16) float cs_lds[64];  // [16 el][4]: new stage state

    // ---- one-time weight preload ----
    float w1r[4][4], b1r[4];
    {
        const int j0 = (wv << 4) + (q << 2);
        #pragma unroll
        for (int u = 0; u < 4; ++u) {
            const int j = j0 + u;
            b1r[u]   = b1[j];
            w1r[0][u] = W1[j];
            w1r[1][u] = W1[64 + j];
            w1r[2][u] = W1[128 + j];
            w1r[3][u] = W1[192 + j];
        }
    }
    // W2^T A-fragments: lane(q,r) holds A[m = r][k = ks*32 + q*8 + t]
    const int col = (wv << 4) + r;
    bf16x8 Wh[2], Wl[2];
    #pragma unroll
    for (int ks = 0; ks < 2; ++ks)
        #pragma unroll
        for (int t = 0; t < 8; ++t) {
            const int k = (ks << 5) + (q << 3) + t;
            const float wgt = W2[(k << 6) + col];
            const short hi = f2bf_trunc(wgt);
            Wh[ks][t] = hi;
            Wl[ks][t] = f2bf_rne(wgt - bf2f(hi));
        }
    // per-lane D rows: c = 16wv + 4q + reg  (reg = 0..3)
    float b2v4[4], w3r[4][3];
    #pragma unroll
    for (int reg = 0; reg < 4; ++reg) {
        const int c = (wv << 4) + (q << 2) + reg;
        b2v4[reg]  = b2[c];
        w3r[reg][0] = W3[c * 3 + 0];
        w3r[reg][1] = W3[c * 3 + 1];
        w3r[reg][2] = W3[c * 3 + 2];
    }
    const float b3v0 = b3[0], b3v1 = b3[1], b3v2 = b3[2];

    // ---- LDS addresses, hoisted ----
    const int slotW = (wv << 1) + (q >> 1);                       // write 16B slot
    const int widx  = (r << 6) + ((slotW ^ (r & 7)) << 3) + ((q & 1) << 2);
    const int ridx0 = (r << 6) + ((q       ^ (r & 7)) << 3);      // ks=0 B-frag
    const int ridx1 = (r << 6) + (((4 | q) ^ (r & 7)) << 3);      // ks=1 B-frag
    const int pswidx = (wv << 6) + (r << 2);                      // q==0 writers

    // ---- state ----
    // cs* live on all lanes (layer-1 input); yb/ka only meaningful on wave 0.
    float yb0 = init_state[el * 3 + 0];
    float yb1 = init_state[el * 3 + 1];
    float yb2 = init_state[el * 3 + 2];
    float cs0 = yb0, cs1 = yb1, cs2 = yb2;
    float ka0 = 0.f, ka1 = 0.f, ka2 = 0.f;

    if (wv == 0 && q == 0) {
        out[(size_t)el * 3 + 0] = yb0;
        out[(size_t)el * 3 + 1] = yb1;
        out[(size_t)el * 3 + 2] = yb2;
    }

    const float* excp = exc + (size_t)el * T_SZ;
    float excB = excp[0];                   // k2..k4 column for step 0
    float excA = excB;                      // k1 column (clipped idx at step 0)
    float tA = tspan[0], tB = tspan[1];

    #pragma unroll 1
    for (int i = 0; i < T_SZ - 1; ++i) {
        // prefetch next step's exc column and t (branch-free clamped index)
        const float excN = excp[(i < T_SZ - 2) ? (i + 1) : (T_SZ - 2)];
        const float tN   = tspan[(i <= T_SZ - 3) ? (i + 2) : (T_SZ - 1)];
        const float dt  = tB - tA;
        const float hdt = 0.5f * dt;

        #pragma unroll
        for (int ev = 0; ev < 4; ++ev) {
            const float excv = (ev == 0) ? excA : excB;
            const float s0 = cs0, s1 = cs1, s2 = cs2;

            // ---- layer 1: this wave's 4 units for element r ----
            uint32_t hi01, hi23, lo01, lo23;
            {
                float hv[4];
                #pragma unroll
                for (int u = 0; u < 4; ++u) {
                    float pre = b1r[u];
                    pre = fmaf(s0,   w1r[0][u], pre);
                    pre = fmaf(s1,   w1r[1][u], pre);
                    pre = fmaf(s2,   w1r[2][u], pre);
                    pre = fmaf(excv, w1r[3][u], pre);
                    hv[u] = fast_tanh(pre);
                }
                const unsigned short h0 = (unsigned short)f2bf_trunc(hv[0]);
                const unsigned short h1_ = (unsigned short)f2bf_trunc(hv[1]);
                const unsigned short h2_ = (unsigned short)f2bf_trunc(hv[2]);
                const unsigned short h3_ = (unsigned short)f2bf_trunc(hv[3]);
                hi01 = (uint32_t)h0 | ((uint32_t)h1_ << 16);
                hi23 = (uint32_t)h2_ | ((uint32_t)h3_ << 16);
                const unsigned short l0 = (unsigned short)f2bf_rne(hv[0] - bf2f((short)h0));
                const unsigned short l1 = (unsigned short)f2bf_rne(hv[1] - bf2f((short)h1_));
                const unsigned short l2 = (unsigned short)f2bf_rne(hv[2] - bf2f((short)h2_));
                const unsigned short l3 = (unsigned short)f2bf_rne(hv[3] - bf2f((short)h3_));
                lo01 = (uint32_t)l0 | ((uint32_t)l1 << 16);
                lo23 = (uint32_t)l2 | ((uint32_t)l3 << 16);
            }
            *reinterpret_cast<uint2*>(&h1hi[widx]) = make_uint2(hi01, hi23);
            *reinterpret_cast<uint2*>(&h1lo[widx]) = make_uint2(lo01, lo23);
            __syncthreads();                              // bar1: h1 ready

            // ---- layer 2 (transposed): A = W2^T frags, B = h1 frags ----
            const bf16x8 Hh0 = *reinterpret_cast<const bf16x8*>(&h1hi[ridx0]);
            const bf16x8 Hh1 = *reinterpret_cast<const bf16x8*>(&h1hi[ridx1]);
            const bf16x8 Hl0 = *reinterpret_cast<const bf16x8*>(&h1lo[ridx0]);
            const bf16x8 Hl1 = *reinterpret_cast<const bf16x8*>(&h1lo[ridx1]);

            f32x4 accA = {b2v4[0], b2v4[1], b2v4[2], b2v4[3]};
            f32x4 accB = {0.f, 0.f, 0.f, 0.f};
            accA = __builtin_amdgcn_mfma_f32_16x16x32_bf16(Wh[0], Hl0, accA, 0, 0, 0);
            accB = __builtin_amdgcn_mfma_f32_16x16x32_bf16(Wh[1], Hl1, accB, 0, 0, 0);
            accA = __builtin_amdgcn_mfma_f32_16x16x32_bf16(Wl[0], Hh0, accA, 0, 0, 0);
            accB = __builtin_amdgcn_mfma_f32_16x16x32_bf16(Wl[1], Hh1, accB, 0, 0, 0);
            accA = __builtin_amdgcn_mfma_f32_16x16x32_bf16(Wh[0], Hh0, accA, 0, 0, 0);
            accB = __builtin_amdgcn_mfma_f32_16x16x32_bf16(Wh[1], Hh1, accB, 0, 0, 0);

            // ---- layer-2 tanh + layer-3 partials (lane-local in element axis) ----
            float p0 = 0.f, p1 = 0.f, p2 = 0.f;
            #pragma unroll
            for (int reg = 0; reg < 4; ++reg) {
                const float h2v = fast_tanh(accA[reg] + accB[reg]);
                p0 = fmaf(h2v, w3r[reg][0], p0);
                p1 = fmaf(h2v, w3r[reg][1], p1);
                p2 = fmaf(h2v, w3r[reg][2], p2);
            }
            // reduce over the 4 q-groups
            p0 += __shfl_xor(p0, 16, 64);
            p1 += __shfl_xor(p1, 16, 64);
            p2 += __shfl_xor(p2, 16, 64);
            p0 += __shfl_xor(p0, 32, 64);
            p1 += __shfl_xor(p1, 32, 64);
            p2 += __shfl_xor(p2, 32, 64);
            if (q == 0) {
                *reinterpret_cast<f32x4*>(&psum[pswidx]) = (f32x4){p0, p1, p2, p2};
            }
            __syncthreads();                              // bar2: psum ready

            // ---- wave 0 only: combine + nn + physics + RK4 + publish cs ----
            if (wv == 0) {
                const f32x4 v0 = *reinterpret_cast<const f32x4*>(&psum[(r << 2)]);
                const f32x4 v1 = *reinterpret_cast<const f32x4*>(&psum[64 + (r << 2)]);
                const f32x4 v2 = *reinterpret_cast<const f32x4*>(&psum[128 + (r << 2)]);
                const f32x4 v3 = *reinterpret_cast<const f32x4*>(&psum[192 + (r << 2)]);
                const float S0 = (v0[0] + v1[0]) + (v2[0] + v3[0]);
                const float S1 = (v0[1] + v1[1]) + (v2[1] + v3[1]);
                const float S2 = (v0[2] + v1[2]) + (v2[2] + v3[2]);

                const float nn0 = C_NN_SCALE * fast_tanh(S0 + b3v0);
                const float nn1 = C_NN_SCALE * fast_tanh(S1 + b3v1);
                const float nn2 = C_NN_SCALE * fast_tanh(S2 + b3v2);

                const float lM  = clampf(s0, C_LMIN, C_LMAX);
                const float act = clampf(s1, 0.01f, 1.0f);
                const float fat = clampf(s2, 0.0f, 1.0f);
                const float a_eff = act * (1.0f - fat);
                const float sin_p = fminf(C_L0SIN * fast_rcp(lM), 0.99f);
                const float cp2   = fmaf(-sin_p, sin_p, 1.0f);
                const float inv_cp = fast_rsq(cp2);
                const float cos_p  = cp2 * inv_cp;
                const float lT   = C_LMT_DEF - lM * cos_p;
                const float epsT = (lT - C_LTS) * C_INV_LTS;
                const float fT   = (epsT > 0.0f) ? C_CT * (__expf(C_KT * epsT) - 1.0f) : 0.0f;
                const float lN   = lM * C_INV_L0;
                const float d1   = lN - 1.0f;
                const float fL   = __expf(-d1 * d1 * (1.0f / 0.45f));
                const float fPE  = (lN > 1.0f) ? (__expf(8.3333333333f * d1) - 1.0f) * C_INV_EM5 : 0.0f;
                const float fV   = (fT * inv_cp - fPE) * fast_rcp(fmaf(a_eff, fL, 0.001f));
                float vN = (fV - 1.0f) * fast_rcp(fmaf(fabsf(fV), C_AF_INV, 1.0f));
                vN = clampf(vN, -1.0f, 1.5f);
                const float r0v = fmaf(C_VMAX_L0, vN, nn0);
                const float g15 = fmaf(1.5f, act, 0.5f);
                const float inv_tau = (excv > act) ? fast_rcp(C_TAU_ACT * g15)
                                                   : g15 * (1.0f / C_TAU_DEACT);
                const float r1v = fmaf(excv - act, inv_tau, nn1);
                const float r2v = C_FAT_RATE * a_eff * (1.0f - fat)
                                - C_REC_RATE * (1.0f - a_eff) * fat + nn2;

                if (ev == 0) {
                    ka0 = r0v; ka1 = r1v; ka2 = r2v;
                    cs0 = fmaf(hdt, r0v, yb0); cs1 = fmaf(hdt, r1v, yb1); cs2 = fmaf(hdt, r2v, yb2);
                } else if (ev == 1) {
                    ka0 = fmaf(2.0f, r0v, ka0); ka1 = fmaf(2.0f, r1v, ka1); ka2 = fmaf(2.0f, r2v, ka2);
                    cs0 = fmaf(hdt, r0v, yb0); cs1 = fmaf(hdt, r1v, yb1); cs2 = fmaf(hdt, r2v, yb2);
                } else if (ev == 2) {
                    ka0 = fmaf(2.0f, r0v, ka0); ka1 = fmaf(2.0f, r1v, ka1); ka2 = fmaf(2.0f, r2v, ka2);
                    cs0 = fmaf(dt, r0v, yb0); cs1 = fmaf(dt, r1v, yb1); cs2 = fmaf(dt, r2v, yb2);
                } else {
                    const float c6 = dt * (1.0f / 6.0f);
                    yb0 = fmaf(c6, ka0 + r0v, yb0);
                    yb1 = fmaf(c6, ka1 + r1v, yb1);
                    yb2 = fmaf(c6, ka2 + r2v, yb2);
                    cs0 = yb0; cs1 = yb1; cs2 = yb2;
                }
                if (q == 0) {
                    *reinterpret_cast<f32x4*>(&cs_lds[r << 2]) = (f32x4){cs0, cs1, cs2, 0.f};
                    if (ev == 3) {
                        const size_t ob = (size_t)(i + 1) * (B_SZ * 3) + (size_t)el * 3;
                        out[ob + 0] = cs0; out[ob + 1] = cs1; out[ob + 2] = cs2;
                    }
                }
            }
            __syncthreads();                              // bar3: cs published

            if (wv != 0) {
                const f32x4 c = *reinterpret_cast<const f32x4*>(&cs_lds[r << 2]);
                cs0 = c[0]; cs1 = c[1]; cs2 = c[2];
            }
        }

        excA = excB; excB = excN; tA = tB; tB = tN;
    }
}

extern "C" void kernel_launch(void* const* d_in, const int* in_sizes, int n_in,
                              void* d_out, int out_size, void* d_ws, size_t ws_size,
                              hipStream_t stream) {
    const float* init  = (const float*)d_in[0];
    const float* exc   = (const float*)d_in[1];
    const float* tspan = (const float*)d_in[2];
    const float* W1    = (const float*)d_in[3];
    const float* b1    = (const float*)d_in[4];
    const float* W2    = (const float*)d_in[5];
    const float* b2    = (const float*)d_in[6];
    const float* W3    = (const float*)d_in[7];
    const float* b3    = (const float*)d_in[8];

    hipLaunchKernelGGL(ode_kernel, dim3(B_SZ / 16), dim3(256), 0, stream,
                       init, exc, tspan, W1, b1, W2, b2, W3, b3, (float*)d_out);
}